// Round 2
// baseline (216.966 us; speedup 1.0000x reference)
//
#include <hip/hip_runtime.h>
#include <math.h>

// ---------------------------------------------------------------------------
// Fused MoE top-2 router, MI355X (gfx950) — round 2.
// R1 was LDS-read-bound (4 B LDS per FMA-lane vs 1 B/cy/lane available).
// New layout: lane = (eg 0..3, ks 0..15); lane accumulates acc[8 tok][16 exp]
// so one 16B LDS read feeds 32 FMAs (W) / 64 FMAs (x). LDS demand ~94 B/cy
// vs 128 B/cy ceiling -> compute-bound at ~27 us FMA floor.
// Both x and W chunks double-buffered in LDS via global_load_lds width-16.
// ---------------------------------------------------------------------------

#define NT 8192
#define ND 4096
#define NE 64
#define TB 32             // tokens per block
#define BK 128            // k per chunk
#define NCHUNK (ND / BK)  // 32

__device__ __forceinline__ void gload16(const float* g, float* l) {
    __builtin_amdgcn_global_load_lds(
        (const __attribute__((address_space(1))) void*)g,
        (__attribute__((address_space(3))) void*)l, 16, 0, 0);
}

__global__ __launch_bounds__(256, 1)
void router_main(const float* __restrict__ x, const float* __restrict__ W,
                 float* __restrict__ out, float* __restrict__ ws)
{
    __shared__ float wbuf[2][NE * BK];   // 2 x 32 KiB
    __shared__ float xbuf[2][TB * BK];   // 2 x 16 KiB
    __shared__ float lg[TB][68];         // block logits, padded stride (16B-aligned)
    __shared__ float load_s[NE];

    const int tid  = threadIdx.x;
    const int wave = tid >> 6;
    const int lane = tid & 63;
    const int eg   = lane >> 4;   // expert group (16 experts each)
    const int ks   = lane & 15;   // k slice

    if (tid < NE) load_s[tid] = 0.f;

    const int tok0 = blockIdx.x * TB;

    float acc[8][16];
    #pragma unroll
    for (int t = 0; t < 8; t++)
        #pragma unroll
        for (int e = 0; e < 16; e++) acc[t][e] = 0.f;

    // prologue: stage chunk 0 into buffer 0
    #pragma unroll
    for (int r = 0; r < 8; r++) {
        int f4 = r * 256 + tid;
        int row = f4 >> 5, col = (f4 & 31) << 2;
        gload16(W + (size_t)row * ND + col, &wbuf[0][f4 << 2]);
    }
    #pragma unroll
    for (int r = 0; r < 4; r++) {
        int f4 = r * 256 + tid;
        int trow = f4 >> 5, col = (f4 & 31) << 2;
        gload16(x + (size_t)(tok0 + trow) * ND + col, &xbuf[0][f4 << 2]);
    }
    __syncthreads();

    for (int c = 0; c < NCHUNK; c++) {
        const int b = c & 1;
        if (c + 1 < NCHUNK) {
            const int koff = (c + 1) * BK;
            #pragma unroll
            for (int r = 0; r < 8; r++) {
                int f4 = r * 256 + tid;
                int row = f4 >> 5, col = (f4 & 31) << 2;
                gload16(W + (size_t)row * ND + koff + col, &wbuf[b ^ 1][f4 << 2]);
            }
            #pragma unroll
            for (int r = 0; r < 4; r++) {
                int f4 = r * 256 + tid;
                int trow = f4 >> 5, col = (f4 & 31) << 2;
                gload16(x + (size_t)(tok0 + trow) * ND + koff + col,
                        &xbuf[b ^ 1][f4 << 2]);
            }
        }

        const float* xb = &xbuf[b][wave * (8 * BK) + ks * 4];
        const float* wb = &wbuf[b][eg * (16 * BK) + ks * 4];

        #pragma unroll
        for (int kk = 0; kk < 2; kk++) {
            float4 xv[8];
            #pragma unroll
            for (int t = 0; t < 8; t++)
                xv[t] = *reinterpret_cast<const float4*>(xb + t * BK + kk * 64);
            #pragma unroll
            for (int es = 0; es < 4; es++) {
                float4 wv[4];
                #pragma unroll
                for (int e2 = 0; e2 < 4; e2++)
                    wv[e2] = *reinterpret_cast<const float4*>(
                        wb + (es * 4 + e2) * BK + kk * 64);
                #pragma unroll
                for (int t = 0; t < 8; t++) {
                    #pragma unroll
                    for (int e2 = 0; e2 < 4; e2++) {
                        float a = acc[t][es * 4 + e2];
                        a = fmaf(xv[t].x, wv[e2].x, a);
                        a = fmaf(xv[t].y, wv[e2].y, a);
                        a = fmaf(xv[t].z, wv[e2].z, a);
                        a = fmaf(xv[t].w, wv[e2].w, a);
                        acc[t][es * 4 + e2] = a;
                    }
                }
            }
        }
        __syncthreads();
    }

    // k-slice reduction (ks = lane bits 0..3; eg groups stay separate)
    #pragma unroll
    for (int t = 0; t < 8; t++)
        #pragma unroll
        for (int e = 0; e < 16; e++) {
            float v = acc[t][e];
            v += __shfl_xor(v, 1);
            v += __shfl_xor(v, 2);
            v += __shfl_xor(v, 4);
            v += __shfl_xor(v, 8);
            acc[t][e] = v;
        }

    // publish logits to LDS (one writer lane per eg)
    if (ks == 0) {
        #pragma unroll
        for (int t = 0; t < 8; t++)
            #pragma unroll
            for (int e4 = 0; e4 < 4; e4++)
                *reinterpret_cast<float4*>(&lg[wave * 8 + t][eg * 16 + e4 * 4]) =
                    make_float4(acc[t][e4 * 4], acc[t][e4 * 4 + 1],
                                acc[t][e4 * 4 + 2], acc[t][e4 * 4 + 3]);
    }
    __syncthreads();

    // ---- epilogue: each thread handles token (tid & 31), 8x redundant ----
    const int t = tid & 31;
    float lgv[NE];
    #pragma unroll
    for (int e4 = 0; e4 < 16; e4++) {
        float4 v = *reinterpret_cast<const float4*>(&lg[t][e4 * 4]);
        lgv[e4 * 4]     = v.x;
        lgv[e4 * 4 + 1] = v.y;
        lgv[e4 * 4 + 2] = v.z;
        lgv[e4 * 4 + 3] = v.w;
    }

    float m = -3.0e38f;
    #pragma unroll
    for (int e = 0; e < NE; e++) m = fmaxf(m, lgv[e]);
    float se = 0.f;
    #pragma unroll
    for (int e = 0; e < NE; e++) se += __expf(lgv[e] - m);
    const float lse = m + __logf(se);
    const float inv = 1.f / se;

    // top-2 (ties: lower index first, matching lax.top_k)
    float v1 = -3.0e38f, v2 = -3.0e38f;
    int   i1 = 0, i2 = 0;
    #pragma unroll
    for (int e = 0; e < NE; e++) {
        const float v = lgv[e];
        if (v > v1)      { v2 = v1; i2 = i1; v1 = v; i1 = e; }
        else if (v > v2) { v2 = v;  i2 = e; }
    }
    const float p1 = __expf(v1 - m) * inv;
    const float p2 = __expf(v2 - m) * inv;
    const float dn = fmaxf(p1 + p2, 1e-9f);

    float ssum = 0.f;
    #pragma unroll
    for (int e = 0; e < NE; e++) ssum += lgv[e];

    if (tid < TB) {
        const int tok = tok0 + t;
        out[2 * tok]              = (float)i1;
        out[2 * tok + 1]          = (float)i2;
        out[2 * NT + 2 * tok]     = p1 / dn;
        out[2 * NT + 2 * tok + 1] = p2 / dn;
        atomicAdd(&load_s[i1], 1.0f);
    }

    // wave 0 (tid<64 holds each token exactly twice): z, logit-sum, importance
    if (tid < 64) {
        float zv = lse * lse, sv = ssum;
        #pragma unroll
        for (int mk = 1; mk < 64; mk <<= 1) {
            zv += __shfl_xor(zv, mk);
            sv += __shfl_xor(sv, mk);
        }
        if (tid == 0) {
            atomicAdd(&ws[128], 0.5f * zv);
            atomicAdd(&ws[129], 0.5f * sv);
        }
        #pragma unroll
        for (int e = 0; e < NE; e++) {
            float v = __expf(lgv[e] - m) * inv;
            #pragma unroll
            for (int mk = 1; mk < 64; mk <<= 1) v += __shfl_xor(v, mk);
            if (tid == e) atomicAdd(&ws[e], 0.5f * v);   // importance[e]
        }
    }

    __syncthreads();
    if (tid < NE) atomicAdd(&ws[NE + tid], load_s[tid]);
}

__global__ void finalize(const float* __restrict__ ws, float* __restrict__ out)
{
    const int l = threadIdx.x;   // one wave
    const float imp = ws[l];
    const float ld  = ws[NE + l];
    float is = imp, ls = ld;
    #pragma unroll
    for (int mk = 1; mk < 64; mk <<= 1) { is += __shfl_xor(is, mk); ls += __shfl_xor(ls, mk); }
    float v = (imp / fmaxf(is, 1e-9f)) * (ld / fmaxf(ls, 1e-9f));
    #pragma unroll
    for (int mk = 1; mk < 64; mk <<= 1) v += __shfl_xor(v, mk);
    if (l == 0) {
        out[4 * NT]     = (ws[128] / (float)NT) * 0.001f;        // router_z_loss
        out[4 * NT + 1] = v * (float)(NE * NE) * 0.01f;          // load_balance_loss
        out[4 * NT + 2] = ws[129] / (float)((size_t)NT * NE);    // logits_mean
    }
}

extern "C" void kernel_launch(void* const* d_in, const int* in_sizes, int n_in,
                              void* d_out, int out_size, void* d_ws, size_t ws_size,
                              hipStream_t stream) {
    const float* x = (const float*)d_in[0];
    const float* W = (const float*)d_in[1];
    float* out = (float*)d_out;
    float* ws  = (float*)d_ws;

    hipMemsetAsync(ws, 0, 130 * sizeof(float), stream);
    hipLaunchKernelGGL(router_main, dim3(NT / TB), dim3(256), 0, stream, x, W, out, ws);
    hipLaunchKernelGGL(finalize, dim3(1), dim3(64), 0, stream, ws, out);
}